// Round 1
// 6009.916 us; speedup vs baseline: 1.2467x; 1.2467x over previous
//
#include <hip/hip_runtime.h>
#include <hip/hip_bf16.h>

// Problem dims
#define VOCAB 50257
#define EMBED 512
#define HIDDEN 1024
#define TSEQ 2048
#define NPAD 50304            // VOCAB padded to multiple of 128
#define LOGITS_SIZE ((size_t)TSEQ * VOCAB)   // 102,926,336

// Workspace layout
#define OFF_XP   ((size_t)0)                          // fp32 [2048][1024]  = 8 MB
#define OFF_HS   ((size_t)(TSEQ * HIDDEN * 4))        // bf16 [2048][1024]  = 4 MB
#define OFF_HP   (OFF_HS + (size_t)TSEQ * HIDDEN * 2) // ull  [2][1024] tagged h pairs = 16 KB
#define OFF_WB   (OFF_HP + 16384 + 256)               // bf16 [50304][1024] = 103 MB
#define WS_NEED_FULL (OFF_WB + (size_t)NPAD * HIDDEN * 2)

typedef short bf16x8 __attribute__((ext_vector_type(8)));
typedef float f32x4  __attribute__((ext_vector_type(4)));
typedef short short8 __attribute__((ext_vector_type(8)));

static __device__ __forceinline__ unsigned short f2bf(float f) {
    unsigned u = __float_as_uint(f);
    unsigned r = (u + 0x7fffu + ((u >> 16) & 1u)) >> 16;
    return (unsigned short)r;
}

// ---------------------------------------------------------------------------
// Kernel 1: xp[t][j] = sum_k emb[x[t]][k] * W_xh[j][k]   (fp32, 64x64 tiles)
// ---------------------------------------------------------------------------
__global__ __launch_bounds__(256, 2) void emb_xp_kernel(
    const int* __restrict__ x, const float* __restrict__ emb,
    const float* __restrict__ Wxh, float* __restrict__ xp)
{
    __shared__ float As[64][68];   // +4 pad: stride 272B (16B-aligned, conflict-free)
    __shared__ float Bs[64][68];
    __shared__ int   xs[64];
    const int tid = threadIdx.x;
    const int t0 = blockIdx.y * 64, j0 = blockIdx.x * 64;
    if (tid < 64) xs[tid] = x[t0 + tid];
    __syncthreads();
    const int ty = tid >> 4, tx = tid & 15;
    float acc[4][4] = {};
    for (int kc = 0; kc < EMBED; kc += 64) {
        __syncthreads();
#pragma unroll
        for (int i = 0; i < 4; ++i) {
            int s = i * 256 + tid;            // 1024 float4 slots
            int r = s >> 4, c4 = s & 15;
            *(float4*)&As[r][c4 * 4] = *(const float4*)&emb[(size_t)xs[r] * EMBED + kc + c4 * 4];
            *(float4*)&Bs[r][c4 * 4] = *(const float4*)&Wxh[(size_t)(j0 + r) * EMBED + kc + c4 * 4];
        }
        __syncthreads();
        for (int kk = 0; kk < 64; ++kk) {
            float a[4], b[4];
#pragma unroll
            for (int u = 0; u < 4; ++u) a[u] = As[ty + 16 * u][kk];
#pragma unroll
            for (int v = 0; v < 4; ++v) b[v] = Bs[tx + 16 * v][kk];
#pragma unroll
            for (int u = 0; u < 4; ++u)
#pragma unroll
                for (int v = 0; v < 4; ++v) acc[u][v] += a[u] * b[v];
        }
    }
#pragma unroll
    for (int u = 0; u < 4; ++u)
#pragma unroll
        for (int v = 0; v < 4; ++v)
            xp[(size_t)(t0 + ty + 16 * u) * HIDDEN + j0 + tx + 16 * v] = acc[u][v];
}

// ---------------------------------------------------------------------------
// Kernel 2: W_out fp32 -> bf16, padded to NPAD rows (pad rows = 0)
// ---------------------------------------------------------------------------
__global__ void conv_wout_kernel(const float* __restrict__ W, unsigned short* __restrict__ Wb)
{
    size_t i = (size_t)blockIdx.x * blockDim.x + threadIdx.x;  // float4 index
    size_t idx = i * 4;
    if (idx >= (size_t)NPAD * HIDDEN) return;
    size_t row = idx >> 10;
    float4 v = make_float4(0.f, 0.f, 0.f, 0.f);
    if (row < VOCAB) v = *(const float4*)&W[idx];
    ushort4 o = make_ushort4(f2bf(v.x), f2bf(v.y), f2bf(v.z), f2bf(v.w));
    *(ushort4*)&Wb[idx] = o;
}

// ---------------------------------------------------------------------------
// Kernel 3: sequential recurrence — barrier-free tagged dataflow.
// 256 WGs x 64 threads (1 wave per CU). Wave w owns j in [w*4, w*4+4);
// 16 threads per j; thread holds 64 W_hh elements in registers.
// Each h element published as one 8B word {tag(hi32)=t+1 | fp32 value(lo32)}
// via relaxed agent-scope atomic store (LLC write-through, single-copy
// atomic). Consumers poll their 64 pairs directly: the successful poll IS
// the data load -> exactly one LLC round trip per step on the critical path.
// Mod-2 buffer reuse is safe: a producer reaches step t+1 only after seeing
// all tags >= t, which proves every wave's reads of slot (t-1)&1 completed.
// ---------------------------------------------------------------------------
#define RNN_WGS 256
__global__ __launch_bounds__(64, 1) void rnn_recur_kernel(
    const float* __restrict__ xp, const float* __restrict__ Whh,
    const float* __restrict__ bhh, unsigned long long* hpair /* [2][1024] */,
    unsigned short* __restrict__ hs_bf16, float* __restrict__ h_final)
{
    const int tid = threadIdx.x;            // 0..63, one wave
    const int j = blockIdx.x * 4 + (tid >> 4);
    const int k16 = tid & 15;

    float4 w4[16];
#pragma unroll
    for (int ii = 0; ii < 16; ++ii)
        w4[ii] = *(const float4*)&Whh[(size_t)j * HIDDEN + ii * 64 + k16 * 4];
    // Pin weights in VGPRs: forbid the compiler from sinking these loads
    // into the t-loop (previous build showed 52 VGPRs => weights were being
    // re-fetched every step).
#pragma unroll
    for (int ii = 0; ii < 16; ++ii)
        asm volatile("" : "+v"(w4[ii].x), "+v"(w4[ii].y), "+v"(w4[ii].z), "+v"(w4[ii].w));
    const float bj = bhh[j];

#pragma unroll 1
    for (int t = 0; t < TSEQ; ++t) {
        unsigned long long* hin  = hpair + ((t & 1) << 10);
        unsigned long long* hout = hpair + (((t + 1) & 1) << 10);
        const float xpv = xp[(size_t)t * HIDDEN + j];   // prefetch (off critical path)

        float hvf[64];
        for (;;) {
            int mn = 0x7fffffff;
#pragma unroll
            for (int ii = 0; ii < 16; ++ii) {
#pragma unroll
                for (int c = 0; c < 4; ++c) {
                    unsigned long long v = __hip_atomic_load(
                        &hin[ii * 64 + k16 * 4 + c],
                        __ATOMIC_RELAXED, __HIP_MEMORY_SCOPE_AGENT);
                    int tag = (int)(unsigned)(v >> 32);
                    mn = tag < mn ? tag : mn;
                    hvf[ii * 4 + c] = __uint_as_float((unsigned)v);
                }
            }
            if (__all(mn >= t)) break;   // wave-uniform exit; success round IS the data
        }

        float sum = 0.f;
#pragma unroll
        for (int ii = 0; ii < 16; ++ii)
            sum += w4[ii].x * hvf[ii * 4 + 0] + w4[ii].y * hvf[ii * 4 + 1]
                 + w4[ii].z * hvf[ii * 4 + 2] + w4[ii].w * hvf[ii * 4 + 3];
        sum += __shfl_xor(sum, 1);
        sum += __shfl_xor(sum, 2);
        sum += __shfl_xor(sum, 4);
        sum += __shfl_xor(sum, 8);

        const float val = tanhf(sum + bj + xpv);
        if (k16 == 0) {
            unsigned long long pk = ((unsigned long long)(unsigned)(t + 1) << 32)
                                  | (unsigned long long)__float_as_uint(val);
            __hip_atomic_store(&hout[j], pk, __ATOMIC_RELAXED, __HIP_MEMORY_SCOPE_AGENT);
            hs_bf16[(size_t)t * HIDDEN + j] = f2bf(val);
            if (t == TSEQ - 1) h_final[j] = val;
        }
    }
}

// ---------------------------------------------------------------------------
// Kernel 4: logits = hs @ W_out.T + b_out.  bf16 MFMA, 128x128 tile,
// 4 waves (2x2), each wave 64x64 via 4x4 of 16x16x32 MFMAs. Register staging.
// ---------------------------------------------------------------------------
template <bool PRE>
__global__ __launch_bounds__(256, 2) void out_gemm_kernel(
    const unsigned short* __restrict__ hs,      // bf16 [2048][1024]
    const unsigned short* __restrict__ Wb,      // bf16 [NPAD][1024]   (PRE)
    const float* __restrict__ Wf,               // fp32 [VOCAB][1024]  (!PRE)
    const float* __restrict__ b_out,
    float* __restrict__ out)
{
    __shared__ short As[128 * 32];
    __shared__ short Bs[128 * 32];
    const int tid = threadIdx.x;
    const int wid = tid >> 6, lane = tid & 63;
    const int wm = wid >> 1, wn = wid & 1;
    const int l15 = lane & 15, quad = lane >> 4;
    const int m0 = blockIdx.y * 128, n0 = blockIdx.x * 128;

    f32x4 acc[4][4];
#pragma unroll
    for (int a = 0; a < 4; ++a)
#pragma unroll
        for (int b = 0; b < 4; ++b) acc[a][b] = (f32x4){0.f, 0.f, 0.f, 0.f};

    for (int k0 = 0; k0 < HIDDEN; k0 += 32) {
        __syncthreads();
        // A tile: [128][32] bf16, rows K-contiguous
#pragma unroll
        for (int i = 0; i < 2; ++i) {
            int ss = i * 256 + tid;
            int r = ss >> 2, c = ss & 3;
            short8 av = *(const short8*)(hs + (size_t)(m0 + r) * HIDDEN + k0 + c * 8);
            *(short8*)&As[r * 32 + c * 8] = av;
        }
        if (PRE) {
#pragma unroll
            for (int i = 0; i < 2; ++i) {
                int ss = i * 256 + tid;
                int r = ss >> 2, c = ss & 3;
                short8 bv = *(const short8*)(Wb + (size_t)(n0 + r) * HIDDEN + k0 + c * 8);
                *(short8*)&Bs[r * 32 + c * 8] = bv;
            }
        } else {
#pragma unroll
            for (int i = 0; i < 4; ++i) {
                int ss = i * 256 + tid;
                int r = ss >> 3, c4 = ss & 7;
                float4 v = make_float4(0.f, 0.f, 0.f, 0.f);
                if (n0 + r < VOCAB) v = *(const float4*)&Wf[(size_t)(n0 + r) * HIDDEN + k0 + c4 * 4];
                ushort4 u = make_ushort4(f2bf(v.x), f2bf(v.y), f2bf(v.z), f2bf(v.w));
                *(ushort4*)&Bs[r * 32 + c4 * 4] = u;
            }
        }
        __syncthreads();

        bf16x8 af[4], bfr[4];
#pragma unroll
        for (int mi = 0; mi < 4; ++mi)
            af[mi] = *(const bf16x8*)&As[(wm * 64 + mi * 16 + l15) * 32 + quad * 8];
#pragma unroll
        for (int ni = 0; ni < 4; ++ni)
            bfr[ni] = *(const bf16x8*)&Bs[(wn * 64 + ni * 16 + l15) * 32 + quad * 8];
#pragma unroll
        for (int mi = 0; mi < 4; ++mi)
#pragma unroll
            for (int ni = 0; ni < 4; ++ni)
                acc[mi][ni] = __builtin_amdgcn_mfma_f32_16x16x32_bf16(af[mi], bfr[ni], acc[mi][ni], 0, 0, 0);
    }

    // Epilogue: C/D layout col = lane&15, row = quad*4 + reg
#pragma unroll
    for (int ni = 0; ni < 4; ++ni) {
        int n = n0 + wn * 64 + ni * 16 + l15;
        bool ok = n < VOCAB;
        float bias = ok ? b_out[n] : 0.f;
#pragma unroll
        for (int mi = 0; mi < 4; ++mi) {
            int mbase = m0 + wm * 64 + mi * 16 + quad * 4;
#pragma unroll
            for (int r = 0; r < 4; ++r) {
                if (ok) out[(size_t)(mbase + r) * VOCAB + n] = acc[mi][ni][r] + bias;
            }
        }
    }
}

// ---------------------------------------------------------------------------
extern "C" void kernel_launch(void* const* d_in, const int* in_sizes, int n_in,
                              void* d_out, int out_size, void* d_ws, size_t ws_size,
                              hipStream_t stream)
{
    const int*   x     = (const int*)d_in[0];
    const float* emb   = (const float*)d_in[1];
    const float* W_xh  = (const float*)d_in[2];
    const float* W_hh  = (const float*)d_in[3];
    const float* b_hh  = (const float*)d_in[4];
    const float* W_out = (const float*)d_in[5];
    const float* b_out = (const float*)d_in[6];
    float* out = (float*)d_out;
    char* ws = (char*)d_ws;

    float*              xp  = (float*)(ws + OFF_XP);
    unsigned short*     hsb = (unsigned short*)(ws + OFF_HS);
    unsigned long long* hp  = (unsigned long long*)(ws + OFF_HP);
    unsigned short*     Wb  = (unsigned short*)(ws + OFF_WB);

    // zero tagged h pairs: slot 0 => {tag=0, h0=0} (valid step-0 input),
    // slot 1 => tag 0 (consumers at t=1 wait for tag>=1). ws is poisoned 0xAA.
    hipMemsetAsync(ws + OFF_HP, 0, 16384, stream);

    emb_xp_kernel<<<dim3(HIDDEN / 64, TSEQ / 64), 256, 0, stream>>>(x, emb, W_xh, xp);

    const bool pre = ws_size >= WS_NEED_FULL;
    if (pre)
        conv_wout_kernel<<<(NPAD * HIDDEN / 4 + 255) / 256, 256, 0, stream>>>(W_out, Wb);

    rnn_recur_kernel<<<RNN_WGS, 64, 0, stream>>>(xp, W_hh, b_hh, hp, hsb,
                                                 out + LOGITS_SIZE);

    if (pre)
        out_gemm_kernel<true><<<dim3(NPAD / 128, TSEQ / 128), 256, 0, stream>>>(
            hsb, Wb, nullptr, b_out, out);
    else
        out_gemm_kernel<false><<<dim3(NPAD / 128, TSEQ / 128), 256, 0, stream>>>(
            hsb, nullptr, W_out, b_out, out);
}

// Round 2
// 5025.960 us; speedup vs baseline: 1.4908x; 1.1958x over previous
//
#include <hip/hip_runtime.h>
#include <hip/hip_bf16.h>

// Problem dims
#define VOCAB 50257
#define EMBED 512
#define HIDDEN 1024
#define TSEQ 2048
#define NPAD 50304            // VOCAB padded to multiple of 128
#define LOGITS_SIZE ((size_t)TSEQ * VOCAB)   // 102,926,336

// Workspace layout
#define OFF_XP   ((size_t)0)                          // fp32 [2048][1024]  = 8 MB
#define OFF_HS   ((size_t)(TSEQ * HIDDEN * 4))        // bf16 [2048][1024]  = 4 MB
#define OFF_HP   (OFF_HS + (size_t)TSEQ * HIDDEN * 2) // ull  [2][1024] tagged h pairs = 16 KB
#define OFF_WB   (OFF_HP + 16384 + 256)               // bf16 [50304][1024] = 103 MB
#define WS_NEED_FULL (OFF_WB + (size_t)NPAD * HIDDEN * 2)

typedef short bf16x8 __attribute__((ext_vector_type(8)));
typedef float f32x4  __attribute__((ext_vector_type(4)));
typedef short short8 __attribute__((ext_vector_type(8)));

static __device__ __forceinline__ unsigned short f2bf(float f) {
    unsigned u = __float_as_uint(f);
    unsigned r = (u + 0x7fffu + ((u >> 16) & 1u)) >> 16;
    return (unsigned short)r;
}

// ---------------------------------------------------------------------------
// Kernel 1: xp[t][j] = sum_k emb[x[t]][k] * W_xh[j][k]   (fp32, 64x64 tiles)
// ---------------------------------------------------------------------------
__global__ __launch_bounds__(256, 2) void emb_xp_kernel(
    const int* __restrict__ x, const float* __restrict__ emb,
    const float* __restrict__ Wxh, float* __restrict__ xp)
{
    __shared__ float As[64][68];   // +4 pad: stride 272B (16B-aligned, conflict-free)
    __shared__ float Bs[64][68];
    __shared__ int   xs[64];
    const int tid = threadIdx.x;
    const int t0 = blockIdx.y * 64, j0 = blockIdx.x * 64;
    if (tid < 64) xs[tid] = x[t0 + tid];
    __syncthreads();
    const int ty = tid >> 4, tx = tid & 15;
    float acc[4][4] = {};
    for (int kc = 0; kc < EMBED; kc += 64) {
        __syncthreads();
#pragma unroll
        for (int i = 0; i < 4; ++i) {
            int s = i * 256 + tid;            // 1024 float4 slots
            int r = s >> 4, c4 = s & 15;
            *(float4*)&As[r][c4 * 4] = *(const float4*)&emb[(size_t)xs[r] * EMBED + kc + c4 * 4];
            *(float4*)&Bs[r][c4 * 4] = *(const float4*)&Wxh[(size_t)(j0 + r) * EMBED + kc + c4 * 4];
        }
        __syncthreads();
        for (int kk = 0; kk < 64; ++kk) {
            float a[4], b[4];
#pragma unroll
            for (int u = 0; u < 4; ++u) a[u] = As[ty + 16 * u][kk];
#pragma unroll
            for (int v = 0; v < 4; ++v) b[v] = Bs[tx + 16 * v][kk];
#pragma unroll
            for (int u = 0; u < 4; ++u)
#pragma unroll
                for (int v = 0; v < 4; ++v) acc[u][v] += a[u] * b[v];
        }
    }
#pragma unroll
    for (int u = 0; u < 4; ++u)
#pragma unroll
        for (int v = 0; v < 4; ++v)
            xp[(size_t)(t0 + ty + 16 * u) * HIDDEN + j0 + tx + 16 * v] = acc[u][v];
}

// ---------------------------------------------------------------------------
// Kernel 2: W_out fp32 -> bf16, padded to NPAD rows (pad rows = 0)
// ---------------------------------------------------------------------------
__global__ void conv_wout_kernel(const float* __restrict__ W, unsigned short* __restrict__ Wb)
{
    size_t i = (size_t)blockIdx.x * blockDim.x + threadIdx.x;  // float4 index
    size_t idx = i * 4;
    if (idx >= (size_t)NPAD * HIDDEN) return;
    size_t row = idx >> 10;
    float4 v = make_float4(0.f, 0.f, 0.f, 0.f);
    if (row < VOCAB) v = *(const float4*)&W[idx];
    ushort4 o = make_ushort4(f2bf(v.x), f2bf(v.y), f2bf(v.z), f2bf(v.w));
    *(ushort4*)&Wb[idx] = o;
}

// ---------------------------------------------------------------------------
// Kernel 3: sequential recurrence — barrier-free tagged dataflow, v2.
// 64 WGs x 256 threads. WG owns j in [wg*16, wg*16+16); 16 threads per j.
// Each h element is one 8B word {tag(hi32)=t+1 | fp32 value(lo32)} published
// with a relaxed agent-scope atomic store (tag+data single-copy atomic ->
// one LLC round trip per step on the critical path, no fences/barrier).
// POLL: each of the 4 waves polls a disjoint 256-word quarter with 4
// perfectly-coalesced 512B loads (vs 64 scattered loads/wave before):
// 16x fewer poll requests per round, cheap wasted rounds. Values land in
// LDS; one __syncthreads; compute reads LDS fragments (conflict-free).
// LDS overwrite at t+1 is safe without a 2nd barrier: poll success at t+1
// proves every WG's waves stored step t, and each store data-depends on
// that wave's LDS reads of step t (reads complete before store exists).
// ---------------------------------------------------------------------------
#define RNN_WGS 64
__global__ __launch_bounds__(256, 1) void rnn_recur_kernel(
    const float* __restrict__ xp, const float* __restrict__ Whh,
    const float* __restrict__ bhh, unsigned long long* hpair /* [2][1024] */,
    unsigned short* __restrict__ hs_bf16, float* __restrict__ h_final)
{
    const int tid  = threadIdx.x;           // 0..255
    const int lane = tid & 63;
    const int wv   = tid >> 6;              // wave 0..3: polls quarter wv
    const int jl   = tid >> 4;              // local j 0..15
    const int j    = blockIdx.x * 16 + jl;
    const int k16  = tid & 15;

    float4 w4[16];
#pragma unroll
    for (int ii = 0; ii < 16; ++ii)
        w4[ii] = *(const float4*)&Whh[(size_t)j * HIDDEN + ii * 64 + k16 * 4];
    // Pin weights in VGPRs (prevent re-fetch inside the t-loop).
#pragma unroll
    for (int ii = 0; ii < 16; ++ii)
        asm volatile("" : "+v"(w4[ii].x), "+v"(w4[ii].y), "+v"(w4[ii].z), "+v"(w4[ii].w));
    const float bj = bhh[j];

    __shared__ float hsm[HIDDEN];
    const int pbase = wv * 256 + lane;      // this thread's poll slot base

#pragma unroll 1
    for (int t = 0; t < TSEQ; ++t) {
        unsigned long long* hin  = hpair + ((t & 1) << 10);
        unsigned long long* hout = hpair + (((t + 1) & 1) << 10);
        const float xpv = xp[(size_t)t * HIDDEN + j];   // off critical path

        unsigned long long v0, v1, v2, v3;
        for (;;) {
            v0 = __hip_atomic_load(&hin[pbase],       __ATOMIC_RELAXED, __HIP_MEMORY_SCOPE_AGENT);
            v1 = __hip_atomic_load(&hin[pbase +  64], __ATOMIC_RELAXED, __HIP_MEMORY_SCOPE_AGENT);
            v2 = __hip_atomic_load(&hin[pbase + 128], __ATOMIC_RELAXED, __HIP_MEMORY_SCOPE_AGENT);
            v3 = __hip_atomic_load(&hin[pbase + 192], __ATOMIC_RELAXED, __HIP_MEMORY_SCOPE_AGENT);
            int t0 = (int)(unsigned)(v0 >> 32), t1 = (int)(unsigned)(v1 >> 32);
            int t2 = (int)(unsigned)(v2 >> 32), t3 = (int)(unsigned)(v3 >> 32);
            int mn = t0 < t1 ? t0 : t1;
            int mn2 = t2 < t3 ? t2 : t3;
            mn = mn < mn2 ? mn : mn2;
            if (__all(mn >= t)) break;      // wave-uniform; success round IS the data
        }
        hsm[pbase]       = __uint_as_float((unsigned)v0);
        hsm[pbase +  64] = __uint_as_float((unsigned)v1);
        hsm[pbase + 128] = __uint_as_float((unsigned)v2);
        hsm[pbase + 192] = __uint_as_float((unsigned)v3);
        __syncthreads();

        float sum = 0.f;
#pragma unroll
        for (int ii = 0; ii < 16; ++ii) {
            float4 h4 = *(const float4*)&hsm[ii * 64 + k16 * 4];
            sum += w4[ii].x * h4.x + w4[ii].y * h4.y + w4[ii].z * h4.z + w4[ii].w * h4.w;
        }
        sum += __shfl_xor(sum, 1);
        sum += __shfl_xor(sum, 2);
        sum += __shfl_xor(sum, 4);
        sum += __shfl_xor(sum, 8);

        const float val = tanhf(sum + bj + xpv);
        if (k16 == 0) {
            unsigned long long pk = ((unsigned long long)(unsigned)(t + 1) << 32)
                                  | (unsigned long long)__float_as_uint(val);
            __hip_atomic_store(&hout[j], pk, __ATOMIC_RELAXED, __HIP_MEMORY_SCOPE_AGENT);
            hs_bf16[(size_t)t * HIDDEN + j] = f2bf(val);
            if (t == TSEQ - 1) h_final[j] = val;
        }
    }
}

// ---------------------------------------------------------------------------
// Kernel 4: logits = hs @ W_out.T + b_out.  bf16 MFMA, 128x128 tile,
// 4 waves (2x2), each wave 64x64 via 4x4 of 16x16x32 MFMAs. Register staging.
// ---------------------------------------------------------------------------
template <bool PRE>
__global__ __launch_bounds__(256, 2) void out_gemm_kernel(
    const unsigned short* __restrict__ hs,      // bf16 [2048][1024]
    const unsigned short* __restrict__ Wb,      // bf16 [NPAD][1024]   (PRE)
    const float* __restrict__ Wf,               // fp32 [VOCAB][1024]  (!PRE)
    const float* __restrict__ b_out,
    float* __restrict__ out)
{
    __shared__ short As[128 * 32];
    __shared__ short Bs[128 * 32];
    const int tid = threadIdx.x;
    const int wid = tid >> 6, lane = tid & 63;
    const int wm = wid >> 1, wn = wid & 1;
    const int l15 = lane & 15, quad = lane >> 4;
    const int m0 = blockIdx.y * 128, n0 = blockIdx.x * 128;

    f32x4 acc[4][4];
#pragma unroll
    for (int a = 0; a < 4; ++a)
#pragma unroll
        for (int b = 0; b < 4; ++b) acc[a][b] = (f32x4){0.f, 0.f, 0.f, 0.f};

    for (int k0 = 0; k0 < HIDDEN; k0 += 32) {
        __syncthreads();
        // A tile: [128][32] bf16, rows K-contiguous
#pragma unroll
        for (int i = 0; i < 2; ++i) {
            int ss = i * 256 + tid;
            int r = ss >> 2, c = ss & 3;
            short8 av = *(const short8*)(hs + (size_t)(m0 + r) * HIDDEN + k0 + c * 8);
            *(short8*)&As[r * 32 + c * 8] = av;
        }
        if (PRE) {
#pragma unroll
            for (int i = 0; i < 2; ++i) {
                int ss = i * 256 + tid;
                int r = ss >> 2, c = ss & 3;
                short8 bv = *(const short8*)(Wb + (size_t)(n0 + r) * HIDDEN + k0 + c * 8);
                *(short8*)&Bs[r * 32 + c * 8] = bv;
            }
        } else {
#pragma unroll
            for (int i = 0; i < 4; ++i) {
                int ss = i * 256 + tid;
                int r = ss >> 3, c4 = ss & 7;
                float4 v = make_float4(0.f, 0.f, 0.f, 0.f);
                if (n0 + r < VOCAB) v = *(const float4*)&Wf[(size_t)(n0 + r) * HIDDEN + k0 + c4 * 4];
                ushort4 u = make_ushort4(f2bf(v.x), f2bf(v.y), f2bf(v.z), f2bf(v.w));
                *(ushort4*)&Bs[r * 32 + c4 * 4] = u;
            }
        }
        __syncthreads();

        bf16x8 af[4], bfr[4];
#pragma unroll
        for (int mi = 0; mi < 4; ++mi)
            af[mi] = *(const bf16x8*)&As[(wm * 64 + mi * 16 + l15) * 32 + quad * 8];
#pragma unroll
        for (int ni = 0; ni < 4; ++ni)
            bfr[ni] = *(const bf16x8*)&Bs[(wn * 64 + ni * 16 + l15) * 32 + quad * 8];
#pragma unroll
        for (int mi = 0; mi < 4; ++mi)
#pragma unroll
            for (int ni = 0; ni < 4; ++ni)
                acc[mi][ni] = __builtin_amdgcn_mfma_f32_16x16x32_bf16(af[mi], bfr[ni], acc[mi][ni], 0, 0, 0);
    }

    // Epilogue: C/D layout col = lane&15, row = quad*4 + reg
#pragma unroll
    for (int ni = 0; ni < 4; ++ni) {
        int n = n0 + wn * 64 + ni * 16 + l15;
        bool ok = n < VOCAB;
        float bias = ok ? b_out[n] : 0.f;
#pragma unroll
        for (int mi = 0; mi < 4; ++mi) {
            int mbase = m0 + wm * 64 + mi * 16 + quad * 4;
#pragma unroll
            for (int r = 0; r < 4; ++r) {
                if (ok) out[(size_t)(mbase + r) * VOCAB + n] = acc[mi][ni][r] + bias;
            }
        }
    }
}

// ---------------------------------------------------------------------------
extern "C" void kernel_launch(void* const* d_in, const int* in_sizes, int n_in,
                              void* d_out, int out_size, void* d_ws, size_t ws_size,
                              hipStream_t stream)
{
    const int*   x     = (const int*)d_in[0];
    const float* emb   = (const float*)d_in[1];
    const float* W_xh  = (const float*)d_in[2];
    const float* W_hh  = (const float*)d_in[3];
    const float* b_hh  = (const float*)d_in[4];
    const float* W_out = (const float*)d_in[5];
    const float* b_out = (const float*)d_in[6];
    float* out = (float*)d_out;
    char* ws = (char*)d_ws;

    float*              xp  = (float*)(ws + OFF_XP);
    unsigned short*     hsb = (unsigned short*)(ws + OFF_HS);
    unsigned long long* hp  = (unsigned long long*)(ws + OFF_HP);
    unsigned short*     Wb  = (unsigned short*)(ws + OFF_WB);

    // zero tagged h pairs: slot 0 => {tag=0, h0=0} (valid step-0 input),
    // slot 1 => tag 0 (consumers at t=1 wait for tag>=1). ws is poisoned 0xAA.
    hipMemsetAsync(ws + OFF_HP, 0, 16384, stream);

    emb_xp_kernel<<<dim3(HIDDEN / 64, TSEQ / 64), 256, 0, stream>>>(x, emb, W_xh, xp);

    const bool pre = ws_size >= WS_NEED_FULL;
    if (pre)
        conv_wout_kernel<<<(NPAD * HIDDEN / 4 + 255) / 256, 256, 0, stream>>>(W_out, Wb);

    rnn_recur_kernel<<<RNN_WGS, 256, 0, stream>>>(xp, W_hh, b_hh, hp, hsb,
                                                  out + LOGITS_SIZE);

    if (pre)
        out_gemm_kernel<true><<<dim3(NPAD / 128, TSEQ / 128), 256, 0, stream>>>(
            hsb, Wb, nullptr, b_out, out);
    else
        out_gemm_kernel<false><<<dim3(NPAD / 128, TSEQ / 128), 256, 0, stream>>>(
            hsb, nullptr, W_out, b_out, out);
}